// Round 5
// baseline (1663.227 us; speedup 1.0000x reference)
//
#include <hip/hip_runtime.h>
#include <math.h>

#define NBR    4        // NUM_BRANCHES
#define REP    1024     // REP_DIM
#define FD     128      // FEAT_DIM
#define NDATA  100000
#define KP1    4097     // NCE_K + 1
#define BN     128      // BATCH
#define MPN    0.04096f // m * Pn = 4096 / 100000
#define EPS_C  1e-7f
#define TINV   (1.0f / 0.07f)

typedef unsigned int   uint4e   __attribute__((ext_vector_type(4)));
typedef unsigned short ushort4e __attribute__((ext_vector_type(4)));

// ---------------------------------------------------------------------------
// bf16 helpers (RNE)
// ---------------------------------------------------------------------------
static __device__ __forceinline__ unsigned short bfbits(unsigned int u) {
    u += 0x7fffu + ((u >> 16) & 1u);
    return (unsigned short)(u >> 16);
}
static __device__ __forceinline__ unsigned short f2bf(float f) {
    union { float f; unsigned int u; } c; c.f = f;
    return bfbits(c.u);
}
static __device__ __forceinline__ float bf2f(unsigned short h) {
    union { unsigned int u; float f; } c; c.u = ((unsigned int)h) << 16;
    return c.f;
}
static __device__ __forceinline__ float lo_of(unsigned int u) {
    union { unsigned int u; float f; } c; c.u = u << 16; return c.f;
}
static __device__ __forceinline__ float hi_of(unsigned int u) {
    union { unsigned int u; float f; } c; c.u = u & 0xffff0000u; return c.f;
}

// ---------------------------------------------------------------------------
// Convert + transpose: dst[n][j][d] (bf16) <- src[j][n][d] (fp32).
// Reads perfectly coalesced + non-temporal (dead copy shouldn't pollute L3);
// writes: 32 consecutive threads write one 256 B contiguous (j,n) segment.
// ---------------------------------------------------------------------------
__global__ void k_convert_t(const float* __restrict__ src, ushort* __restrict__ dst) {
    const size_t t = (size_t)blockIdx.x * 256 + threadIdx.x;  // quad id
    const size_t total = (size_t)NBR * NDATA * 32;            // 12.8M quads
    if (t >= total) return;
    unsigned int jn = (unsigned int)(t >> 5);
    unsigned int q  = (unsigned int)(t & 31);
    unsigned int j  = jn / (unsigned int)NDATA;
    unsigned int n  = jn - j * (unsigned int)NDATA;
    uint4e v = __builtin_nontemporal_load((const uint4e*)src + t);
    ushort4e o;
    o.x = bfbits(v.x); o.y = bfbits(v.y); o.z = bfbits(v.z); o.w = bfbits(v.w);
    ((ushort4e*)dst)[((size_t)n * NBR + j) * 32 + q] = o;
}

// ---------------------------------------------------------------------------
// h[r,b,d] = sum_i emb_r[b,i] * W[r,d,i] + bias;  e = h/||h||
// grid (NBR, BN), block 128
// ---------------------------------------------------------------------------
__global__ void k_feat(const float* __restrict__ e0, const float* __restrict__ e1,
                       const float* __restrict__ e2, const float* __restrict__ e3,
                       const float* __restrict__ W, const float* __restrict__ bias,
                       float* __restrict__ e_out) {
    const int r = blockIdx.x;
    const int b = blockIdx.y;
    const float* emb = (r == 0 ? e0 : r == 1 ? e1 : r == 2 ? e2 : e3) + (size_t)b * REP;

    __shared__ float s_emb[REP];
    for (int i = threadIdx.x; i < REP; i += blockDim.x) s_emb[i] = emb[i];
    __syncthreads();

    const int d = threadIdx.x;
    const float4* wrow = (const float4*)(W + ((size_t)r * FD + d) * REP);
    float acc = 0.f;
#pragma unroll 8
    for (int c = 0; c < REP / 4; ++c) {
        float4 v = wrow[c];
        acc += v.x * s_emb[4*c+0] + v.y * s_emb[4*c+1]
             + v.z * s_emb[4*c+2] + v.w * s_emb[4*c+3];
    }
    float h = acc + bias[r * FD + d];

    __shared__ float red[FD];
    red[d] = h * h;
    __syncthreads();
    for (int off = FD / 2; off > 0; off >>= 1) {
        if (d < off) red[d] += red[d + off];
        __syncthreads();
    }
    float nrm = sqrtf(red[0]);
    e_out[((size_t)r * BN + b) * FD + d] = h / nrm;
}

// ---------------------------------------------------------------------------
// Pass 1, wave-cooperative: one wave processes one item (b,k) at a time.
// Row n = cidx[b,k] in transposed layout is 1 KB contiguous -> ONE wave-wide
// dwordx4 load (lane L holds j=L>>4, d=(L&15)*8 .. +8). e-slices pinned in
// 32 regs/lane. Cross-lane reduce via 4 shfl_xor steps within 16-lane groups.
// grid (16, BN), block 256 (4 waves); wave w handles k = w, w+64, ...
// expS layout: [b][k][j][i] bf16 (leader lane of each j-group stores 8 B).
// ---------------------------------------------------------------------------
__global__ __launch_bounds__(256)
void k_pass1w(const float* __restrict__ e, const ushort* __restrict__ memT,
              const int* __restrict__ cidx, float* __restrict__ Zsum,
              ushort* __restrict__ expS) {
    const int b    = blockIdx.y;
    const int lane = threadIdx.x & 63;
    const int wid  = (threadIdx.x >> 6) + (blockIdx.x << 2);  // [0, 64)
    const int nw   = gridDim.x << 2;                          // 64
    const int j    = lane >> 4;
    const int d0   = (lane & 15) * 8;

    // e[i][b][d0..d0+8) into registers
    float er[4][8];
#pragma unroll
    for (int i = 0; i < 4; ++i) {
        const float4* ep = (const float4*)(e + ((size_t)i * BN + b) * FD + d0);
        float4 v0 = ep[0], v1 = ep[1];
        er[i][0] = v0.x; er[i][1] = v0.y; er[i][2] = v0.z; er[i][3] = v0.w;
        er[i][4] = v1.x; er[i][5] = v1.y; er[i][6] = v1.z; er[i][7] = v1.w;
    }

    const int*   ci  = cidx + (size_t)b * KP1;
    const uint4* mt  = (const uint4*)memT;
    ushort*      esb = expS + (size_t)b * (KP1 * 16);

    float z0 = 0.f, z1 = 0.f, z2 = 0.f, z3 = 0.f;

    int k = wid;
    uint4 buf;
    if (k < KP1) {
        int n = ci[k];
        buf = mt[(size_t)n * 64 + lane];
    }
    while (k < KP1) {
        const int k2 = k + nw;
        uint4 cur = buf;
        if (k2 < KP1) {                       // prefetch next item's row
            int n2 = ci[k2];
            buf = mt[(size_t)n2 * 64 + lane];
        }

        float a0 = 0.f, a1 = 0.f, a2 = 0.f, a3 = 0.f;
#pragma unroll
        for (int q = 0; q < 4; ++q) {
            unsigned int u = (&cur.x)[q];
            float wl = lo_of(u), wh = hi_of(u);
            a0 += wl * er[0][q*2] + wh * er[0][q*2+1];
            a1 += wl * er[1][q*2] + wh * er[1][q*2+1];
            a2 += wl * er[2][q*2] + wh * er[2][q*2+1];
            a3 += wl * er[3][q*2] + wh * er[3][q*2+1];
        }
        // sum the 16 d-chunks of this j-group (butterfly -> all lanes get sum)
#pragma unroll
        for (int off = 1; off < 16; off <<= 1) {
            a0 += __shfl_xor(a0, off, 64);
            a1 += __shfl_xor(a1, off, 64);
            a2 += __shfl_xor(a2, off, 64);
            a3 += __shfl_xor(a3, off, 64);
        }
        float x0 = __expf(a0 * TINV), x1 = __expf(a1 * TINV);
        float x2 = __expf(a2 * TINV), x3 = __expf(a3 * TINV);
        z0 += x0; z1 += x1; z2 += x2; z3 += x3;

        if ((lane & 15) == 0) {               // 4 leader lanes store 32 B total
            ushort4e st;
            st.x = f2bf(x0); st.y = f2bf(x1); st.z = f2bf(x2); st.w = f2bf(x3);
            *(ushort4e*)(esb + (size_t)k * 16 + j * 4) = st;
        }
        k = k2;
    }

    // all 16 lanes of a j-group hold identical z -> leader adds. Zsum[i*4+j].
    if ((lane & 15) == 0) {
        atomicAdd(&Zsum[0  + j], z0);
        atomicAdd(&Zsum[4  + j], z1);
        atomicAdd(&Zsum[8  + j], z2);
        atomicAdd(&Zsum[12 + j], z3);
    }
}

// ---------------------------------------------------------------------------
// Pass 2: stream expS ([b][k][j][i], 32 B/item), accumulate 16 log-term sums.
// accum layout [j*4+i] (storage order). grid (8, BN), block 256, 2 items/thr.
// ---------------------------------------------------------------------------
static __device__ __forceinline__ void acc_words(unsigned int w0, unsigned int w1,
                                                 unsigned int w2, unsigned int w3,
                                                 unsigned int w4, unsigned int w5,
                                                 unsigned int w6, unsigned int w7,
                                                 const float* __restrict__ s_zinv,
                                                 float* __restrict__ acc, bool pos) {
    unsigned int wds[8] = {w0, w1, w2, w3, w4, w5, w6, w7};
#pragma unroll
    for (int w = 0; w < 8; ++w) {
        float v0 = lo_of(wds[w]) * s_zinv[2*w];
        float v1 = hi_of(wds[w]) * s_zinv[2*w+1];
        if (pos) {
            acc[2*w]   += -__logf(1.f + (MPN + EPS_C) / v0);
            acc[2*w+1] += -__logf(1.f + (MPN + EPS_C) / v1);
        } else {
            acc[2*w]   += -__logf(1.f + (v0 + EPS_C) * (1.f / MPN));
            acc[2*w+1] += -__logf(1.f + (v1 + EPS_C) * (1.f / MPN));
        }
    }
}

__global__ __launch_bounds__(256)
void k_pass2f(const uint4* __restrict__ expS, const float* __restrict__ Zsum,
              float* __restrict__ accum) {
    const int b = blockIdx.y;

    __shared__ float s_zinv[16];   // [j*4+i]
    if (threadIdx.x < 16) {
        int jj = threadIdx.x >> 2, ii = threadIdx.x & 3;
        float Z = Zsum[ii * 4 + jj] *
                  (float)((double)NDATA / ((double)BN * (double)KP1));
        s_zinv[threadIdx.x] = 1.0f / Z;
    }
    __syncthreads();

    const uint4* es = expS + (size_t)b * (KP1 * 2);
    const int base = threadIdx.x + blockIdx.x * 256;   // [0, 2048)

    float acc[16];
#pragma unroll
    for (int t = 0; t < 16; ++t) acc[t] = 0.f;

#pragma unroll
    for (int it = 0; it < 2; ++it) {
        const int k = base + it * 2048;
        uint4 p0 = es[(size_t)k * 2];
        uint4 p1 = es[(size_t)k * 2 + 1];
        acc_words(p0.x, p0.y, p0.z, p0.w, p1.x, p1.y, p1.z, p1.w,
                  s_zinv, acc, k == 0);
    }
    if (base == 0) {   // tail k = 4096
        uint4 p0 = es[(size_t)4096 * 2];
        uint4 p1 = es[(size_t)4096 * 2 + 1];
        acc_words(p0.x, p0.y, p0.z, p0.w, p1.x, p1.y, p1.z, p1.w,
                  s_zinv, acc, false);
    }

#pragma unroll
    for (int t = 0; t < 16; ++t) {
        float v = acc[t];
#pragma unroll
        for (int off = 32; off > 0; off >>= 1) v += __shfl_down(v, off, 64);
        if ((threadIdx.x & 63) == 0) atomicAdd(&accum[t], v);
    }
}

// ---------------------------------------------------------------------------
// fp32 fallback pieces (only used if workspace too small for the full path)
// ---------------------------------------------------------------------------
static __device__ __forceinline__ void dot4(const float4* __restrict__ row,
                                            const float* __restrict__ se,
                                            float& a0, float& a1, float& a2, float& a3) {
    a0 = a1 = a2 = a3 = 0.f;
#pragma unroll 8
    for (int c = 0; c < FD / 4; ++c) {
        float4 v = row[c];
        const int o = 4 * c;
        a0 += v.x * se[0*FD+o+0] + v.y * se[0*FD+o+1] + v.z * se[0*FD+o+2] + v.w * se[0*FD+o+3];
        a1 += v.x * se[1*FD+o+0] + v.y * se[1*FD+o+1] + v.z * se[1*FD+o+2] + v.w * se[1*FD+o+3];
        a2 += v.x * se[2*FD+o+0] + v.y * se[2*FD+o+1] + v.z * se[2*FD+o+2] + v.w * se[2*FD+o+3];
        a3 += v.x * se[3*FD+o+0] + v.y * se[3*FD+o+1] + v.z * se[3*FD+o+2] + v.w * se[3*FD+o+3];
    }
}

static __device__ __forceinline__ void block_reduce4(float z0, float z1, float z2,
                                                     float z3, float* dst, int j) {
    __shared__ float sred[256];
    float zs[NBR] = {z0, z1, z2, z3};
    for (int i = 0; i < NBR; ++i) {
        sred[threadIdx.x] = zs[i];
        __syncthreads();
        for (int off = 128; off > 0; off >>= 1) {
            if ((int)threadIdx.x < off) sred[threadIdx.x] += sred[threadIdx.x + off];
            __syncthreads();
        }
        if (threadIdx.x == 0) atomicAdd(&dst[i * NBR + j], sred[0]);
        __syncthreads();
    }
}

static __device__ __forceinline__ float term_of(float ex, float zinv, int k) {
    const float c = MPN + EPS_C;
    float v = ex * zinv;
    if (k == 0) return -__logf(1.0f + c / v);
    return -__logf(1.0f + (v + EPS_C) * (1.0f / MPN));
}

template <bool STORE>
__global__ void k_pass1_f32(const float* __restrict__ e, const float* __restrict__ memory,
                            const int* __restrict__ cidx,
                            float* __restrict__ Zsum, ushort4* __restrict__ expS) {
    const int j = blockIdx.z;
    const int b = blockIdx.y;

    __shared__ float s_e[NBR * FD];
    for (int t = threadIdx.x; t < NBR * FD; t += blockDim.x) {
        int i = t >> 7, d = t & (FD - 1);
        s_e[t] = e[((size_t)i * BN + b) * FD + d];
    }
    __syncthreads();

    const int* ci = cidx + (size_t)b * KP1;
    const float4* mem4 = (const float4*)(memory + (size_t)j * NDATA * FD);
    float z0 = 0.f, z1 = 0.f, z2 = 0.f, z3 = 0.f;

    for (int k = threadIdx.x + blockIdx.x * blockDim.x; k < KP1;
         k += blockDim.x * gridDim.x) {
        const int n = ci[k];
        const float4* row = mem4 + (size_t)n * (FD / 4);
        float a0, a1, a2, a3;
        dot4(row, s_e, a0, a1, a2, a3);
        float x0 = __expf(a0 * TINV);
        float x1 = __expf(a1 * TINV);
        float x2 = __expf(a2 * TINV);
        float x3 = __expf(a3 * TINV);
        z0 += x0; z1 += x1; z2 += x2; z3 += x3;
        if (STORE) {
            ushort4 st;
            st.x = f2bf(x0); st.y = f2bf(x1); st.z = f2bf(x2); st.w = f2bf(x3);
            expS[((size_t)j * BN + b) * KP1 + k] = st;
        }
    }
    block_reduce4(z0, z1, z2, z3, Zsum, j);
}

__global__ void k_pass2_stored(const ushort4* __restrict__ expS,
                               const float* __restrict__ Zsum,
                               float* __restrict__ accum) {
    const int j = blockIdx.z;
    const int b = blockIdx.y;

    __shared__ float s_zinv[NBR];
    if (threadIdx.x < NBR) {
        float Z = Zsum[threadIdx.x * NBR + j] *
                  (float)((double)NDATA / ((double)BN * (double)KP1));
        s_zinv[threadIdx.x] = 1.0f / Z;
    }
    __syncthreads();

    const ushort4* es = expS + ((size_t)j * BN + b) * KP1;
    float a0 = 0.f, a1 = 0.f, a2 = 0.f, a3 = 0.f;

    for (int k = threadIdx.x + blockIdx.x * blockDim.x; k < KP1;
         k += blockDim.x * gridDim.x) {
        ushort4 v = es[k];
        a0 += term_of(bf2f(v.x), s_zinv[0], k);
        a1 += term_of(bf2f(v.y), s_zinv[1], k);
        a2 += term_of(bf2f(v.z), s_zinv[2], k);
        a3 += term_of(bf2f(v.w), s_zinv[3], k);
    }
    block_reduce4(a0, a1, a2, a3, accum, j);
}

__global__ void k_pass2_regather(const float* __restrict__ e, const float* __restrict__ memory,
                                 const int* __restrict__ cidx,
                                 const float* __restrict__ Zsum, float* __restrict__ accum) {
    const int j = blockIdx.z;
    const int b = blockIdx.y;

    __shared__ float s_e[NBR * FD];
    __shared__ float s_zinv[NBR];
    for (int t = threadIdx.x; t < NBR * FD; t += blockDim.x) {
        int i = t >> 7, d = t & (FD - 1);
        s_e[t] = e[((size_t)i * BN + b) * FD + d];
    }
    if (threadIdx.x < NBR) {
        float Z = Zsum[threadIdx.x * NBR + j] *
                  (float)((double)NDATA / ((double)BN * (double)KP1));
        s_zinv[threadIdx.x] = 1.0f / Z;
    }
    __syncthreads();

    const int* ci = cidx + (size_t)b * KP1;
    const float4* mem4 = (const float4*)(memory + (size_t)j * NDATA * FD);
    float a0s = 0.f, a1s = 0.f, a2s = 0.f, a3s = 0.f;

    for (int k = threadIdx.x + blockIdx.x * blockDim.x; k < KP1;
         k += blockDim.x * gridDim.x) {
        const int n = ci[k];
        const float4* row = mem4 + (size_t)n * (FD / 4);
        float a0, a1, a2, a3;
        dot4(row, s_e, a0, a1, a2, a3);
        a0s += term_of(__expf(a0 * TINV), s_zinv[0], k);
        a1s += term_of(__expf(a1 * TINV), s_zinv[1], k);
        a2s += term_of(__expf(a2 * TINV), s_zinv[2], k);
        a3s += term_of(__expf(a3 * TINV), s_zinv[3], k);
    }
    block_reduce4(a0s, a1s, a2s, a3s, accum, j);
}

// ---------------------------------------------------------------------------
__global__ void k_init(float* __restrict__ p) {
    if (threadIdx.x < 32) p[threadIdx.x] = 0.f;  // Zsum[16] + accum[16]
}

// Sums ALL off-diagonal accum entries -> orientation of accum layout is
// irrelevant (mask is symmetric and we sum every i!=j cell exactly once).
__global__ void k_final(const float* __restrict__ accum, float* __restrict__ out) {
    if (threadIdx.x == 0) {
        float s = 0.f;
        for (int i = 0; i < NBR; ++i)
            for (int j = 0; j < NBR; ++j)
                if (i != j) s += -accum[i * NBR + j] / (float)BN;
        out[0] = s;
    }
}

// ---------------------------------------------------------------------------
extern "C" void kernel_launch(void* const* d_in, const int* in_sizes, int n_in,
                              void* d_out, int out_size, void* d_ws, size_t ws_size,
                              hipStream_t stream) {
    const float* e0   = (const float*)d_in[0];
    const float* e1   = (const float*)d_in[1];
    const float* e2   = (const float*)d_in[2];
    const float* e3   = (const float*)d_in[3];
    const float* W    = (const float*)d_in[4];
    const float* bias = (const float*)d_in[5];
    const float* mem  = (const float*)d_in[6];
    const int*   cidx = (const int*)d_in[8];
    float* out = (float*)d_out;

    // workspace: e[65536] f32 | Zsum[16] | accum[16] | memT bf16 | expS
    float* ws    = (float*)d_ws;
    float* e     = ws;
    float* Zsum  = ws + 65536;
    float* accum = ws + 65552;
    const size_t base_b  = (size_t)65568 * 4;              // 262,272 B
    const size_t memT_b  = (size_t)NDATA * NBR * FD * 2;   // 102,400,000 B
    const size_t expS_b  = (size_t)BN * KP1 * 16 * 2;      // 16,781,312 B

    const size_t need_full = base_b + memT_b + expS_b;     // ~119.4 MB
    const size_t need_mid  = base_b + expS_b;              // ~17.0 MB

    k_init<<<1, 64, 0, stream>>>(Zsum);
    k_feat<<<dim3(NBR, BN), 128, 0, stream>>>(e0, e1, e2, e3, W, bias, e);

    if (ws_size >= need_full) {
        ushort* memT = (ushort*)((char*)d_ws + base_b);
        ushort* expS = (ushort*)((char*)d_ws + base_b + memT_b);
        k_convert_t<<<50000, 256, 0, stream>>>(mem, memT);
        k_pass1w<<<dim3(16, BN), 256, 0, stream>>>(e, memT, cidx, Zsum, expS);
        k_pass2f<<<dim3(8, BN), 256, 0, stream>>>((const uint4*)expS, Zsum, accum);
    } else if (ws_size >= need_mid) {
        ushort4* expS = (ushort4*)((char*)d_ws + base_b);
        k_pass1_f32<true><<<dim3(4, BN, NBR), 256, 0, stream>>>(e, mem, cidx, Zsum, expS);
        k_pass2_stored<<<dim3(4, BN, NBR), 256, 0, stream>>>(expS, Zsum, accum);
    } else {
        k_pass1_f32<false><<<dim3(4, BN, NBR), 256, 0, stream>>>(e, mem, cidx, Zsum, nullptr);
        k_pass2_regather<<<dim3(4, BN, NBR), 256, 0, stream>>>(e, mem, cidx, Zsum, accum);
    }
    k_final<<<1, 64, 0, stream>>>(accum, out);
}

// Round 6
// 473.017 us; speedup vs baseline: 3.5162x; 3.5162x over previous
//
#include <hip/hip_runtime.h>
#include <math.h>

#define NBR    4        // NUM_BRANCHES
#define REP    1024     // REP_DIM
#define FD     128      // FEAT_DIM
#define NDATA  100000
#define KP1    4097     // NCE_K + 1
#define BN     128      // BATCH
#define MPN    0.04096f // m * Pn = 4096 / 100000
#define EPS_C  1e-7f
#define TINV   (1.0f / 0.07f)
#define NSLOT  64       // atomic slots (cachelines) for partial sums

typedef unsigned int   uint4e   __attribute__((ext_vector_type(4)));
typedef unsigned short ushort4e __attribute__((ext_vector_type(4)));

// ---------------------------------------------------------------------------
// bf16 helpers (RNE)
// ---------------------------------------------------------------------------
static __device__ __forceinline__ unsigned short bfbits(unsigned int u) {
    u += 0x7fffu + ((u >> 16) & 1u);
    return (unsigned short)(u >> 16);
}
static __device__ __forceinline__ unsigned short f2bf(float f) {
    union { float f; unsigned int u; } c; c.f = f;
    return bfbits(c.u);
}
static __device__ __forceinline__ float bf2f(unsigned short h) {
    union { unsigned int u; float f; } c; c.u = ((unsigned int)h) << 16;
    return c.f;
}
static __device__ __forceinline__ float lo_of(unsigned int u) {
    union { unsigned int u; float f; } c; c.u = u << 16; return c.f;
}
static __device__ __forceinline__ float hi_of(unsigned int u) {
    union { unsigned int u; float f; } c; c.u = u & 0xffff0000u; return c.f;
}

// ---------------------------------------------------------------------------
// Convert + transpose: dst[n][j][d] (bf16) <- src[j][n][d] (fp32).
// ---------------------------------------------------------------------------
__global__ void k_convert_t(const float* __restrict__ src, ushort* __restrict__ dst) {
    const size_t t = (size_t)blockIdx.x * 256 + threadIdx.x;  // quad id
    const size_t total = (size_t)NBR * NDATA * 32;            // 12.8M quads
    if (t >= total) return;
    unsigned int jn = (unsigned int)(t >> 5);
    unsigned int q  = (unsigned int)(t & 31);
    unsigned int j  = jn / (unsigned int)NDATA;
    unsigned int n  = jn - j * (unsigned int)NDATA;
    uint4e v = __builtin_nontemporal_load((const uint4e*)src + t);
    ushort4e o;
    o.x = bfbits(v.x); o.y = bfbits(v.y); o.z = bfbits(v.z); o.w = bfbits(v.w);
    ((ushort4e*)dst)[((size_t)n * NBR + j) * 32 + q] = o;
}

// ---------------------------------------------------------------------------
// h[r,b,d] = sum_i emb_r[b,i] * W[r,d,i] + bias;  e = h/||h||
// grid (NBR, BN), block 128
// ---------------------------------------------------------------------------
__global__ void k_feat(const float* __restrict__ e0, const float* __restrict__ e1,
                       const float* __restrict__ e2, const float* __restrict__ e3,
                       const float* __restrict__ W, const float* __restrict__ bias,
                       float* __restrict__ e_out) {
    const int r = blockIdx.x;
    const int b = blockIdx.y;
    const float* emb = (r == 0 ? e0 : r == 1 ? e1 : r == 2 ? e2 : e3) + (size_t)b * REP;

    __shared__ float s_emb[REP];
    for (int i = threadIdx.x; i < REP; i += blockDim.x) s_emb[i] = emb[i];
    __syncthreads();

    const int d = threadIdx.x;
    const float4* wrow = (const float4*)(W + ((size_t)r * FD + d) * REP);
    float acc = 0.f;
#pragma unroll 8
    for (int c = 0; c < REP / 4; ++c) {
        float4 v = wrow[c];
        acc += v.x * s_emb[4*c+0] + v.y * s_emb[4*c+1]
             + v.z * s_emb[4*c+2] + v.w * s_emb[4*c+3];
    }
    float h = acc + bias[r * FD + d];

    __shared__ float red[FD];
    red[d] = h * h;
    __syncthreads();
    for (int off = FD / 2; off > 0; off >>= 1) {
        if (d < off) red[d] += red[d + off];
        __syncthreads();
    }
    float nrm = sqrtf(red[0]);
    e_out[((size_t)r * BN + b) * FD + d] = h / nrm;
}

// ---------------------------------------------------------------------------
// Pass 1, wave-cooperative: one wave per item (b,k); row n = cidx[b,k] is
// 1 KB contiguous in memT -> one wave-wide dwordx4 load (lane L: j=L>>4,
// d=(L&15)*8..+8). Butterfly-reduce within 16-lane j-groups.
// Zsum partials: LDS cross-wave reduce -> ONE 16-lane atomic instr per block
// into Zsl[slot][16] (slot = lbid & 63) -- avoids same-line atomic drain
// (R5 lesson: same-cacheline atomics serialize at ~31 cyc/instr).
// grid (16, BN), block 256. expS layout: [b][k][j][i] bf16.
// ---------------------------------------------------------------------------
__global__ __launch_bounds__(256)
void k_pass1w(const float* __restrict__ e, const ushort* __restrict__ memT,
              const int* __restrict__ cidx, float* __restrict__ Zsl,
              ushort* __restrict__ expS) {
    const int b    = blockIdx.y;
    const int lane = threadIdx.x & 63;
    const int w    = threadIdx.x >> 6;
    const int wid  = w + (blockIdx.x << 2);   // [0, 64)
    const int nw   = gridDim.x << 2;          // 64
    const int j    = lane >> 4;
    const int d0   = (lane & 15) * 8;

    float er[4][8];
#pragma unroll
    for (int i = 0; i < 4; ++i) {
        const float4* ep = (const float4*)(e + ((size_t)i * BN + b) * FD + d0);
        float4 v0 = ep[0], v1 = ep[1];
        er[i][0] = v0.x; er[i][1] = v0.y; er[i][2] = v0.z; er[i][3] = v0.w;
        er[i][4] = v1.x; er[i][5] = v1.y; er[i][6] = v1.z; er[i][7] = v1.w;
    }

    const int*   ci  = cidx + (size_t)b * KP1;
    const uint4* mt  = (const uint4*)memT;
    ushort*      esb = expS + (size_t)b * (KP1 * 16);

    float z0 = 0.f, z1 = 0.f, z2 = 0.f, z3 = 0.f;

    int k = wid;
    uint4 buf;
    if (k < KP1) {
        int n = ci[k];
        buf = mt[(size_t)n * 64 + lane];
    }
    while (k < KP1) {
        const int k2 = k + nw;
        uint4 cur = buf;
        if (k2 < KP1) {
            int n2 = ci[k2];
            buf = mt[(size_t)n2 * 64 + lane];
        }

        float a0 = 0.f, a1 = 0.f, a2 = 0.f, a3 = 0.f;
#pragma unroll
        for (int q = 0; q < 4; ++q) {
            unsigned int u = (&cur.x)[q];
            float wl = lo_of(u), wh = hi_of(u);
            a0 += wl * er[0][q*2] + wh * er[0][q*2+1];
            a1 += wl * er[1][q*2] + wh * er[1][q*2+1];
            a2 += wl * er[2][q*2] + wh * er[2][q*2+1];
            a3 += wl * er[3][q*2] + wh * er[3][q*2+1];
        }
#pragma unroll
        for (int off = 1; off < 16; off <<= 1) {
            a0 += __shfl_xor(a0, off, 64);
            a1 += __shfl_xor(a1, off, 64);
            a2 += __shfl_xor(a2, off, 64);
            a3 += __shfl_xor(a3, off, 64);
        }
        float x0 = __expf(a0 * TINV), x1 = __expf(a1 * TINV);
        float x2 = __expf(a2 * TINV), x3 = __expf(a3 * TINV);
        z0 += x0; z1 += x1; z2 += x2; z3 += x3;

        if ((lane & 15) == 0) {
            ushort4e st;
            st.x = f2bf(x0); st.y = f2bf(x1); st.z = f2bf(x2); st.w = f2bf(x3);
            *(ushort4e*)(esb + (size_t)k * 16 + j * 4) = st;
        }
        k = k2;
    }

    // cross-wave LDS reduce -> one coalesced 16-lane atomic per block
    __shared__ float s_z[4][16];   // [wave][i*4+j]
    if ((lane & 15) == 0) {
        s_z[w][0*4 + j] = z0;
        s_z[w][1*4 + j] = z1;
        s_z[w][2*4 + j] = z2;
        s_z[w][3*4 + j] = z3;
    }
    __syncthreads();
    if (threadIdx.x < 16) {
        float v = s_z[0][threadIdx.x] + s_z[1][threadIdx.x]
                + s_z[2][threadIdx.x] + s_z[3][threadIdx.x];
        const int slot = (blockIdx.y * gridDim.x + blockIdx.x) & (NSLOT - 1);
        atomicAdd(&Zsl[slot * 16 + threadIdx.x], v);
    }
}

// ---------------------------------------------------------------------------
// Zsl[64][16] -> Zsum[16]  (layout [i*4+j])
// ---------------------------------------------------------------------------
__global__ void k_zred(const float* __restrict__ Zsl, float* __restrict__ Zsum) {
    if (threadIdx.x < 16) {
        float s = 0.f;
        for (int sl = 0; sl < NSLOT; ++sl) s += Zsl[sl * 16 + threadIdx.x];
        Zsum[threadIdx.x] = s;
    }
}

// ---------------------------------------------------------------------------
// Pass 2: stream expS ([b][k][j][i], 32 B/item), accumulate 16 log-term sums.
// Partials: wave shfl reduce -> LDS cross-wave -> one 16-lane atomic per
// block into Asl[slot][16]. grid (8, BN), block 256, 2 items/thread.
// ---------------------------------------------------------------------------
static __device__ __forceinline__ void acc_words(unsigned int w0, unsigned int w1,
                                                 unsigned int w2, unsigned int w3,
                                                 unsigned int w4, unsigned int w5,
                                                 unsigned int w6, unsigned int w7,
                                                 const float* __restrict__ s_zinv,
                                                 float* __restrict__ acc, bool pos) {
    unsigned int wds[8] = {w0, w1, w2, w3, w4, w5, w6, w7};
#pragma unroll
    for (int w = 0; w < 8; ++w) {
        float v0 = lo_of(wds[w]) * s_zinv[2*w];
        float v1 = hi_of(wds[w]) * s_zinv[2*w+1];
        if (pos) {
            acc[2*w]   += -__logf(1.f + (MPN + EPS_C) / v0);
            acc[2*w+1] += -__logf(1.f + (MPN + EPS_C) / v1);
        } else {
            acc[2*w]   += -__logf(1.f + (v0 + EPS_C) * (1.f / MPN));
            acc[2*w+1] += -__logf(1.f + (v1 + EPS_C) * (1.f / MPN));
        }
    }
}

__global__ __launch_bounds__(256)
void k_pass2f(const uint4* __restrict__ expS, const float* __restrict__ Zsum,
              float* __restrict__ Asl) {
    const int b = blockIdx.y;

    __shared__ float s_zinv[16];   // [j*4+i]
    if (threadIdx.x < 16) {
        int jj = threadIdx.x >> 2, ii = threadIdx.x & 3;
        float Z = Zsum[ii * 4 + jj] *
                  (float)((double)NDATA / ((double)BN * (double)KP1));
        s_zinv[threadIdx.x] = 1.0f / Z;
    }
    __syncthreads();

    const uint4* es = expS + (size_t)b * (KP1 * 2);
    const int base = threadIdx.x + blockIdx.x * 256;   // [0, 2048)

    float acc[16];
#pragma unroll
    for (int t = 0; t < 16; ++t) acc[t] = 0.f;

#pragma unroll
    for (int it = 0; it < 2; ++it) {
        const int k = base + it * 2048;
        uint4 p0 = es[(size_t)k * 2];
        uint4 p1 = es[(size_t)k * 2 + 1];
        acc_words(p0.x, p0.y, p0.z, p0.w, p1.x, p1.y, p1.z, p1.w,
                  s_zinv, acc, k == 0);
    }
    if (base == 0) {   // tail k = 4096
        uint4 p0 = es[(size_t)4096 * 2];
        uint4 p1 = es[(size_t)4096 * 2 + 1];
        acc_words(p0.x, p0.y, p0.z, p0.w, p1.x, p1.y, p1.z, p1.w,
                  s_zinv, acc, false);
    }

#pragma unroll
    for (int t = 0; t < 16; ++t) {
#pragma unroll
        for (int off = 32; off > 0; off >>= 1)
            acc[t] += __shfl_down(acc[t], off, 64);
    }
    __shared__ float s_a[4][16];
    const int w = threadIdx.x >> 6;
    if ((threadIdx.x & 63) == 0) {
#pragma unroll
        for (int t = 0; t < 16; ++t) s_a[w][t] = acc[t];
    }
    __syncthreads();
    if (threadIdx.x < 16) {
        float v = s_a[0][threadIdx.x] + s_a[1][threadIdx.x]
                + s_a[2][threadIdx.x] + s_a[3][threadIdx.x];
        const int slot = (blockIdx.y * gridDim.x + blockIdx.x) & (NSLOT - 1);
        atomicAdd(&Asl[slot * 16 + threadIdx.x], v);
    }
}

// ---------------------------------------------------------------------------
// Asl[64][16] -> masked loss.  comp c = (j<<2)|i; off-diag iff i != j.
// ---------------------------------------------------------------------------
__global__ void k_final_slots(const float* __restrict__ Asl, float* __restrict__ out) {
    const int tid = threadIdx.x;              // 256
    const int comp = tid & 15;
    const int grp  = tid >> 4;                // 16 groups
    float a = 0.f;
    for (int sl = grp; sl < NSLOT; sl += 16) a += Asl[sl * 16 + comp];
    const float m = ((comp >> 2) != (comp & 3)) ? 1.f : 0.f;
    __shared__ float s[256];
    s[tid] = a * m;
    __syncthreads();
    for (int off = 128; off > 0; off >>= 1) {
        if (tid < off) s[tid] += s[tid + off];
        __syncthreads();
    }
    if (tid == 0) out[0] = -s[0] / (float)BN;
}

// ---------------------------------------------------------------------------
// fp32 fallback pieces (only if workspace too small for the full path)
// ---------------------------------------------------------------------------
static __device__ __forceinline__ void dot4(const float4* __restrict__ row,
                                            const float* __restrict__ se,
                                            float& a0, float& a1, float& a2, float& a3) {
    a0 = a1 = a2 = a3 = 0.f;
#pragma unroll 8
    for (int c = 0; c < FD / 4; ++c) {
        float4 v = row[c];
        const int o = 4 * c;
        a0 += v.x * se[0*FD+o+0] + v.y * se[0*FD+o+1] + v.z * se[0*FD+o+2] + v.w * se[0*FD+o+3];
        a1 += v.x * se[1*FD+o+0] + v.y * se[1*FD+o+1] + v.z * se[1*FD+o+2] + v.w * se[1*FD+o+3];
        a2 += v.x * se[2*FD+o+0] + v.y * se[2*FD+o+1] + v.z * se[2*FD+o+2] + v.w * se[2*FD+o+3];
        a3 += v.x * se[3*FD+o+0] + v.y * se[3*FD+o+1] + v.z * se[3*FD+o+2] + v.w * se[3*FD+o+3];
    }
}

static __device__ __forceinline__ void block_reduce4(float z0, float z1, float z2,
                                                     float z3, float* dst, int j) {
    __shared__ float sred[256];
    float zs[NBR] = {z0, z1, z2, z3};
    for (int i = 0; i < NBR; ++i) {
        sred[threadIdx.x] = zs[i];
        __syncthreads();
        for (int off = 128; off > 0; off >>= 1) {
            if ((int)threadIdx.x < off) sred[threadIdx.x] += sred[threadIdx.x + off];
            __syncthreads();
        }
        if (threadIdx.x == 0) atomicAdd(&dst[i * NBR + j], sred[0]);
        __syncthreads();
    }
}

static __device__ __forceinline__ float term_of(float ex, float zinv, int k) {
    const float c = MPN + EPS_C;
    float v = ex * zinv;
    if (k == 0) return -__logf(1.0f + c / v);
    return -__logf(1.0f + (v + EPS_C) * (1.0f / MPN));
}

template <bool STORE>
__global__ void k_pass1_f32(const float* __restrict__ e, const float* __restrict__ memory,
                            const int* __restrict__ cidx,
                            float* __restrict__ Zsum, ushort4* __restrict__ expS) {
    const int j = blockIdx.z;
    const int b = blockIdx.y;

    __shared__ float s_e[NBR * FD];
    for (int t = threadIdx.x; t < NBR * FD; t += blockDim.x) {
        int i = t >> 7, d = t & (FD - 1);
        s_e[t] = e[((size_t)i * BN + b) * FD + d];
    }
    __syncthreads();

    const int* ci = cidx + (size_t)b * KP1;
    const float4* mem4 = (const float4*)(memory + (size_t)j * NDATA * FD);
    float z0 = 0.f, z1 = 0.f, z2 = 0.f, z3 = 0.f;

    for (int k = threadIdx.x + blockIdx.x * blockDim.x; k < KP1;
         k += blockDim.x * gridDim.x) {
        const int n = ci[k];
        const float4* row = mem4 + (size_t)n * (FD / 4);
        float a0, a1, a2, a3;
        dot4(row, s_e, a0, a1, a2, a3);
        float x0 = __expf(a0 * TINV);
        float x1 = __expf(a1 * TINV);
        float x2 = __expf(a2 * TINV);
        float x3 = __expf(a3 * TINV);
        z0 += x0; z1 += x1; z2 += x2; z3 += x3;
        if (STORE) {
            ushort4 st;
            st.x = f2bf(x0); st.y = f2bf(x1); st.z = f2bf(x2); st.w = f2bf(x3);
            expS[((size_t)j * BN + b) * KP1 + k] = st;
        }
    }
    block_reduce4(z0, z1, z2, z3, Zsum, j);
}

__global__ void k_pass2_stored(const ushort4* __restrict__ expS,
                               const float* __restrict__ Zsum,
                               float* __restrict__ accum) {
    const int j = blockIdx.z;
    const int b = blockIdx.y;

    __shared__ float s_zinv[NBR];
    if (threadIdx.x < NBR) {
        float Z = Zsum[threadIdx.x * NBR + j] *
                  (float)((double)NDATA / ((double)BN * (double)KP1));
        s_zinv[threadIdx.x] = 1.0f / Z;
    }
    __syncthreads();

    const ushort4* es = expS + ((size_t)j * BN + b) * KP1;
    float a0 = 0.f, a1 = 0.f, a2 = 0.f, a3 = 0.f;

    for (int k = threadIdx.x + blockIdx.x * blockDim.x; k < KP1;
         k += blockDim.x * gridDim.x) {
        ushort4 v = es[k];
        a0 += term_of(bf2f(v.x), s_zinv[0], k);
        a1 += term_of(bf2f(v.y), s_zinv[1], k);
        a2 += term_of(bf2f(v.z), s_zinv[2], k);
        a3 += term_of(bf2f(v.w), s_zinv[3], k);
    }
    block_reduce4(a0, a1, a2, a3, accum, j);
}

__global__ void k_pass2_regather(const float* __restrict__ e, const float* __restrict__ memory,
                                 const int* __restrict__ cidx,
                                 const float* __restrict__ Zsum, float* __restrict__ accum) {
    const int j = blockIdx.z;
    const int b = blockIdx.y;

    __shared__ float s_e[NBR * FD];
    __shared__ float s_zinv[NBR];
    for (int t = threadIdx.x; t < NBR * FD; t += blockDim.x) {
        int i = t >> 7, d = t & (FD - 1);
        s_e[t] = e[((size_t)i * BN + b) * FD + d];
    }
    if (threadIdx.x < NBR) {
        float Z = Zsum[threadIdx.x * NBR + j] *
                  (float)((double)NDATA / ((double)BN * (double)KP1));
        s_zinv[threadIdx.x] = 1.0f / Z;
    }
    __syncthreads();

    const int* ci = cidx + (size_t)b * KP1;
    const float4* mem4 = (const float4*)(memory + (size_t)j * NDATA * FD);
    float a0s = 0.f, a1s = 0.f, a2s = 0.f, a3s = 0.f;

    for (int k = threadIdx.x + blockIdx.x * blockDim.x; k < KP1;
         k += blockDim.x * gridDim.x) {
        const int n = ci[k];
        const float4* row = mem4 + (size_t)n * (FD / 4);
        float a0, a1, a2, a3;
        dot4(row, s_e, a0, a1, a2, a3);
        a0s += term_of(__expf(a0 * TINV), s_zinv[0], k);
        a1s += term_of(__expf(a1 * TINV), s_zinv[1], k);
        a2s += term_of(__expf(a2 * TINV), s_zinv[2], k);
        a3s += term_of(__expf(a3 * TINV), s_zinv[3], k);
    }
    block_reduce4(a0s, a1s, a2s, a3s, accum, j);
}

// ---------------------------------------------------------------------------
__global__ void k_init(float* __restrict__ p, int n) {
    int i = blockIdx.x * blockDim.x + threadIdx.x;
    if (i < n) p[i] = 0.f;
}

__global__ void k_final_legacy(const float* __restrict__ accum, float* __restrict__ out) {
    if (threadIdx.x == 0) {
        float s = 0.f;
        for (int i = 0; i < NBR; ++i)
            for (int j = 0; j < NBR; ++j)
                if (i != j) s += -accum[i * NBR + j] / (float)BN;
        out[0] = s;
    }
}

// ---------------------------------------------------------------------------
extern "C" void kernel_launch(void* const* d_in, const int* in_sizes, int n_in,
                              void* d_out, int out_size, void* d_ws, size_t ws_size,
                              hipStream_t stream) {
    const float* e0   = (const float*)d_in[0];
    const float* e1   = (const float*)d_in[1];
    const float* e2   = (const float*)d_in[2];
    const float* e3   = (const float*)d_in[3];
    const float* W    = (const float*)d_in[4];
    const float* bias = (const float*)d_in[5];
    const float* mem  = (const float*)d_in[6];
    const int*   cidx = (const int*)d_in[8];
    float* out = (float*)d_out;

    // ws (floats): e[65536] | Zsum[16] | accum[16] | Zsl[1024] | Asl[1024] | memT | expS
    float* ws    = (float*)d_ws;
    float* e     = ws;
    float* Zsum  = ws + 65536;
    float* accum = ws + 65552;
    float* Zsl   = ws + 65568;
    float* Asl   = ws + 66592;
    const size_t base_b = (size_t)67616 * 4;             // 270,464 B (16-aligned)
    const size_t memT_b = (size_t)NDATA * NBR * FD * 2;  // 102,400,000 B
    const size_t expS_b = (size_t)BN * KP1 * 16 * 2;     // 16,781,312 B

    const size_t need_full = base_b + memT_b + expS_b;   // ~119.45 MB
    const size_t need_mid  = base_b + expS_b;            // ~17.05 MB

    k_init<<<9, 256, 0, stream>>>(Zsum, 2080);  // Zsum+accum+Zsl+Asl
    k_feat<<<dim3(NBR, BN), 128, 0, stream>>>(e0, e1, e2, e3, W, bias, e);

    if (ws_size >= need_full) {
        ushort* memT = (ushort*)((char*)d_ws + base_b);
        ushort* expS = (ushort*)((char*)d_ws + base_b + memT_b);
        k_convert_t<<<50000, 256, 0, stream>>>(mem, memT);
        k_pass1w<<<dim3(16, BN), 256, 0, stream>>>(e, memT, cidx, Zsl, expS);
        k_zred<<<1, 64, 0, stream>>>(Zsl, Zsum);
        k_pass2f<<<dim3(8, BN), 256, 0, stream>>>((const uint4*)expS, Zsum, Asl);
        k_final_slots<<<1, 256, 0, stream>>>(Asl, out);
    } else if (ws_size >= need_mid) {
        ushort4* expS = (ushort4*)((char*)d_ws + base_b);
        k_pass1_f32<true><<<dim3(4, BN, NBR), 256, 0, stream>>>(e, mem, cidx, Zsum, expS);
        k_pass2_stored<<<dim3(4, BN, NBR), 256, 0, stream>>>(expS, Zsum, accum);
        k_final_legacy<<<1, 64, 0, stream>>>(accum, out);
    } else {
        k_pass1_f32<false><<<dim3(4, BN, NBR), 256, 0, stream>>>(e, mem, cidx, Zsum, nullptr);
        k_pass2_regather<<<dim3(4, BN, NBR), 256, 0, stream>>>(e, mem, cidx, Zsum, accum);
        k_final_legacy<<<1, 64, 0, stream>>>(accum, out);
    }
}

// Round 7
// 426.568 us; speedup vs baseline: 3.8991x; 1.1089x over previous
//
#include <hip/hip_runtime.h>
#include <math.h>

#define NBR    4        // NUM_BRANCHES
#define REP    1024     // REP_DIM
#define FD     128      // FEAT_DIM
#define NDATA  100000
#define KP1    4097     // NCE_K + 1
#define BN     128      // BATCH
#define MPN    0.04096f // m * Pn = 4096 / 100000
#define EPS_C  1e-7f
#define TINV   (1.0f / 0.07f)
#define NSLOT  64       // atomic slots (cachelines) for partial sums

typedef unsigned int   uint4e   __attribute__((ext_vector_type(4)));
typedef unsigned short ushort4e __attribute__((ext_vector_type(4)));
typedef _Float16       half2e   __attribute__((ext_vector_type(2)));

// ---------------------------------------------------------------------------
// fp16 / bf16 helpers
// ---------------------------------------------------------------------------
static __device__ __forceinline__ unsigned short f2h(float f) {
    union { _Float16 h; unsigned short u; } c; c.h = (_Float16)f; return c.u;
}
static __device__ __forceinline__ float h_lo(unsigned int u) {
    union { unsigned int u; _Float16 h[2]; } c; c.u = u; return (float)c.h[0];
}
static __device__ __forceinline__ float h_hi(unsigned int u) {
    union { unsigned int u; _Float16 h[2]; } c; c.u = u; return (float)c.h[1];
}
static __device__ __forceinline__ half2e u2h2(unsigned int u) {
    union { unsigned int u; half2e h; } c; c.u = u; return c.h;
}
static __device__ __forceinline__ unsigned short f2bf(float f) {
    union { float f; unsigned int u; } c; c.f = f;
    unsigned int u = c.u;
    u += 0x7fffu + ((u >> 16) & 1u);
    return (unsigned short)(u >> 16);
}
static __device__ __forceinline__ float bf2f(unsigned short h) {
    union { unsigned int u; float f; } c; c.u = ((unsigned int)h) << 16;
    return c.f;
}

// ---------------------------------------------------------------------------
// Convert + transpose: dst[n][j][d] (f16) <- src[j][n][d] (fp32).
// f16 keeps |w|<=0.16 at rel err 2^-11 (better than bf16). Non-temporal reads.
// ---------------------------------------------------------------------------
__global__ void k_convert_t(const float* __restrict__ src, ushort* __restrict__ dst) {
    const size_t t = (size_t)blockIdx.x * 256 + threadIdx.x;  // quad id
    const size_t total = (size_t)NBR * NDATA * 32;            // 12.8M quads
    if (t >= total) return;
    unsigned int jn = (unsigned int)(t >> 5);
    unsigned int q  = (unsigned int)(t & 31);
    unsigned int j  = jn / (unsigned int)NDATA;
    unsigned int n  = jn - j * (unsigned int)NDATA;
    uint4e v = __builtin_nontemporal_load((const uint4e*)src + t);
    union { unsigned int u; float f; } c0, c1, c2, c3;
    c0.u = v.x; c1.u = v.y; c2.u = v.z; c3.u = v.w;
    ushort4e o;
    o.x = f2h(c0.f); o.y = f2h(c1.f); o.z = f2h(c2.f); o.w = f2h(c3.f);
    ((ushort4e*)dst)[((size_t)n * NBR + j) * 32 + q] = o;
}

// ---------------------------------------------------------------------------
// h[r,b,d] = sum_i emb_r[b,i] * W[r,d,i] + bias;  e = h/||h||
// grid (NBR, BN), block 128
// ---------------------------------------------------------------------------
__global__ void k_feat(const float* __restrict__ e0, const float* __restrict__ e1,
                       const float* __restrict__ e2, const float* __restrict__ e3,
                       const float* __restrict__ W, const float* __restrict__ bias,
                       float* __restrict__ e_out) {
    const int r = blockIdx.x;
    const int b = blockIdx.y;
    const float* emb = (r == 0 ? e0 : r == 1 ? e1 : r == 2 ? e2 : e3) + (size_t)b * REP;

    __shared__ float s_emb[REP];
    for (int i = threadIdx.x; i < REP; i += blockDim.x) s_emb[i] = emb[i];
    __syncthreads();

    const int d = threadIdx.x;
    const float4* wrow = (const float4*)(W + ((size_t)r * FD + d) * REP);
    float acc = 0.f;
#pragma unroll 8
    for (int c = 0; c < REP / 4; ++c) {
        float4 v = wrow[c];
        acc += v.x * s_emb[4*c+0] + v.y * s_emb[4*c+1]
             + v.z * s_emb[4*c+2] + v.w * s_emb[4*c+3];
    }
    float h = acc + bias[r * FD + d];

    __shared__ float red[FD];
    red[d] = h * h;
    __syncthreads();
    for (int off = FD / 2; off > 0; off >>= 1) {
        if (d < off) red[d] += red[d + off];
        __syncthreads();
    }
    float nrm = sqrtf(red[0]);
    e_out[((size_t)r * BN + b) * FD + d] = h / nrm;
}

// ---------------------------------------------------------------------------
// Pass 1, wave-cooperative, f16 + fdot2 + folded butterfly + 2-deep prefetch.
// One wave per item (b,k); row n = cidx[b,k] is 1 KB contiguous in memT ->
// one wave-wide dwordx4 load (lane L: j=L>>4, d=(L&15)*8..+8).
// Folded reduce: step1 (xor8) folds (a0,a2)/(a1,a3); step2 (xor4) folds
// (c0,c1); steps 3,4 plain butterfly -> lane 16j+4i+r holds S_i (i=(b3<<1)|b2).
// 5 shfl + 1 exp per item (was 16 shfl + 4 exp).
// Zsum partials: slotted 16-lane atomic per block (R5 lesson: same-line
// atomics serialize ~31cyc/instr).
// grid (16, BN), block 256. expS layout: [b][k][j][i] f16.
// ---------------------------------------------------------------------------
__global__ __launch_bounds__(256)
void k_pass1w(const float* __restrict__ e, const ushort* __restrict__ memT,
              const int* __restrict__ cidx, float* __restrict__ Zsl,
              ushort* __restrict__ expS) {
    const int b    = blockIdx.y;
    const int lane = threadIdx.x & 63;
    const int w    = threadIdx.x >> 6;
    const int wid  = w + (blockIdx.x << 2);   // [0, 64)
    const int nw   = gridDim.x << 2;          // 64
    const int l4   = lane & 15;
    const int d0   = l4 * 8;
    const bool b3  = (l4 & 8) != 0;
    const bool b2  = (l4 & 4) != 0;

    // e[i][b][d0..d0+8) as 4x half2 per i
    half2e eh[4][4];
#pragma unroll
    for (int i = 0; i < 4; ++i) {
        const float4* ep = (const float4*)(e + ((size_t)i * BN + b) * FD + d0);
        float4 v0 = ep[0], v1 = ep[1];
        eh[i][0] = half2e{(_Float16)v0.x, (_Float16)v0.y};
        eh[i][1] = half2e{(_Float16)v0.z, (_Float16)v0.w};
        eh[i][2] = half2e{(_Float16)v1.x, (_Float16)v1.y};
        eh[i][3] = half2e{(_Float16)v1.z, (_Float16)v1.w};
    }

    const int*   ci  = cidx + (size_t)b * KP1;
    const uint4* mt  = (const uint4*)memT;
    ushort*      esb = expS + (size_t)b * (KP1 * 16);

    float z = 0.f;

    int k = wid;
    uint4 A, B;
    if (k < KP1)      A = mt[(size_t)ci[k] * 64 + lane];
    if (k + nw < KP1) B = mt[(size_t)ci[k + nw] * 64 + lane];

    for (; k < KP1; k += nw) {
        uint4 cur = A;
        A = B;
        const int kpf = k + 2 * nw;
        if (kpf < KP1) B = mt[(size_t)ci[kpf] * 64 + lane];

        float a0 = 0.f, a1 = 0.f, a2 = 0.f, a3 = 0.f;
#pragma unroll
        for (int q = 0; q < 4; ++q) {
            half2e hw = u2h2((&cur.x)[q]);
            a0 = __builtin_amdgcn_fdot2(hw, eh[0][q], a0, false);
            a1 = __builtin_amdgcn_fdot2(hw, eh[1][q], a1, false);
            a2 = __builtin_amdgcn_fdot2(hw, eh[2][q], a2, false);
            a3 = __builtin_amdgcn_fdot2(hw, eh[3][q], a3, false);
        }
        // folded butterfly within 16-lane j-group
        float t0 = __shfl_xor(b3 ? a0 : a2, 8, 64);
        float t1 = __shfl_xor(b3 ? a1 : a3, 8, 64);
        float c0 = (b3 ? a2 : a0) + t0;
        float c1 = (b3 ? a3 : a1) + t1;
        float t2 = __shfl_xor(b2 ? c0 : c1, 4, 64);
        float d  = (b2 ? c1 : c0) + t2;
        d += __shfl_xor(d, 2, 64);
        d += __shfl_xor(d, 1, 64);
        // lane 16j+4i+r now holds S_i summed over all 16 lanes of group j
        float x = __expf(d * TINV);
        z += x;
        if ((lane & 3) == 0)   // 16 leader lanes: 2B each, contiguous 32B/item
            esb[(size_t)k * 16 + (lane >> 2)] = f2h(x);
    }

    // cross-wave LDS reduce -> one coalesced 16-lane atomic per block
    __shared__ float s_z[4][16];   // [wave][i*4+j]
    const int j = lane >> 4;
    const int i = ((l4 >> 3) << 1) | ((l4 >> 2) & 1);
    if ((lane & 3) == 0) s_z[w][i * 4 + j] = z;
    __syncthreads();
    if (threadIdx.x < 16) {
        float v = s_z[0][threadIdx.x] + s_z[1][threadIdx.x]
                + s_z[2][threadIdx.x] + s_z[3][threadIdx.x];
        const int slot = (blockIdx.y * gridDim.x + blockIdx.x) & (NSLOT - 1);
        atomicAdd(&Zsl[slot * 16 + threadIdx.x], v);
    }
}

// ---------------------------------------------------------------------------
// Zsl[64][16] -> Zsum[16]  (layout [i*4+j])
// ---------------------------------------------------------------------------
__global__ void k_zred(const float* __restrict__ Zsl, float* __restrict__ Zsum) {
    if (threadIdx.x < 16) {
        float s = 0.f;
        for (int sl = 0; sl < NSLOT; ++sl) s += Zsl[sl * 16 + threadIdx.x];
        Zsum[threadIdx.x] = s;
    }
}

// ---------------------------------------------------------------------------
// Pass 2: stream expS ([b][k][j][i], f16, 32 B/item), accumulate 16 log-term
// sums. Slotted 16-lane atomics. grid (8, BN), block 256, 2 items/thread.
// ---------------------------------------------------------------------------
static __device__ __forceinline__ void acc_words(const uint4& p0, const uint4& p1,
                                                 const float* __restrict__ s_zinv,
                                                 float* __restrict__ acc, bool pos) {
    unsigned int wds[8] = {p0.x, p0.y, p0.z, p0.w, p1.x, p1.y, p1.z, p1.w};
#pragma unroll
    for (int w = 0; w < 8; ++w) {
        float v0 = h_lo(wds[w]) * s_zinv[2*w];
        float v1 = h_hi(wds[w]) * s_zinv[2*w+1];
        if (pos) {
            acc[2*w]   += -__logf(1.f + (MPN + EPS_C) / v0);
            acc[2*w+1] += -__logf(1.f + (MPN + EPS_C) / v1);
        } else {
            acc[2*w]   += -__logf(1.f + (v0 + EPS_C) * (1.f / MPN));
            acc[2*w+1] += -__logf(1.f + (v1 + EPS_C) * (1.f / MPN));
        }
    }
}

__global__ __launch_bounds__(256)
void k_pass2f(const uint4* __restrict__ expS, const float* __restrict__ Zsum,
              float* __restrict__ Asl) {
    const int b = blockIdx.y;

    __shared__ float s_zinv[16];   // [j*4+i]
    if (threadIdx.x < 16) {
        int jj = threadIdx.x >> 2, ii = threadIdx.x & 3;
        float Z = Zsum[ii * 4 + jj] *
                  (float)((double)NDATA / ((double)BN * (double)KP1));
        s_zinv[threadIdx.x] = 1.0f / Z;
    }
    __syncthreads();

    const uint4* es = expS + (size_t)b * (KP1 * 2);
    const int base = threadIdx.x + blockIdx.x * 256;   // [0, 2048)

    float acc[16];
#pragma unroll
    for (int t = 0; t < 16; ++t) acc[t] = 0.f;

#pragma unroll
    for (int it = 0; it < 2; ++it) {
        const int k = base + it * 2048;
        uint4 p0 = es[(size_t)k * 2];
        uint4 p1 = es[(size_t)k * 2 + 1];
        acc_words(p0, p1, s_zinv, acc, k == 0);
    }
    if (base == 0) {   // tail k = 4096
        uint4 p0 = es[(size_t)4096 * 2];
        uint4 p1 = es[(size_t)4096 * 2 + 1];
        acc_words(p0, p1, s_zinv, acc, false);
    }

#pragma unroll
    for (int t = 0; t < 16; ++t) {
#pragma unroll
        for (int off = 32; off > 0; off >>= 1)
            acc[t] += __shfl_down(acc[t], off, 64);
    }
    __shared__ float s_a[4][16];
    const int w = threadIdx.x >> 6;
    if ((threadIdx.x & 63) == 0) {
#pragma unroll
        for (int t = 0; t < 16; ++t) s_a[w][t] = acc[t];
    }
    __syncthreads();
    if (threadIdx.x < 16) {
        float v = s_a[0][threadIdx.x] + s_a[1][threadIdx.x]
                + s_a[2][threadIdx.x] + s_a[3][threadIdx.x];
        const int slot = (blockIdx.y * gridDim.x + blockIdx.x) & (NSLOT - 1);
        atomicAdd(&Asl[slot * 16 + threadIdx.x], v);
    }
}

// ---------------------------------------------------------------------------
// Asl[64][16] -> masked loss.  comp c = j*4+i; off-diag iff i != j.
// ---------------------------------------------------------------------------
__global__ void k_final_slots(const float* __restrict__ Asl, float* __restrict__ out) {
    const int tid = threadIdx.x;              // 256
    const int comp = tid & 15;
    const int grp  = tid >> 4;                // 16 groups
    float a = 0.f;
    for (int sl = grp; sl < NSLOT; sl += 16) a += Asl[sl * 16 + comp];
    const float m = ((comp >> 2) != (comp & 3)) ? 1.f : 0.f;
    __shared__ float s[256];
    s[tid] = a * m;
    __syncthreads();
    for (int off = 128; off > 0; off >>= 1) {
        if (tid < off) s[tid] += s[tid + off];
        __syncthreads();
    }
    if (tid == 0) out[0] = -s[0] / (float)BN;
}

// ---------------------------------------------------------------------------
// fp32 fallback pieces (only if workspace too small for the full path)
// ---------------------------------------------------------------------------
static __device__ __forceinline__ void dot4(const float4* __restrict__ row,
                                            const float* __restrict__ se,
                                            float& a0, float& a1, float& a2, float& a3) {
    a0 = a1 = a2 = a3 = 0.f;
#pragma unroll 8
    for (int c = 0; c < FD / 4; ++c) {
        float4 v = row[c];
        const int o = 4 * c;
        a0 += v.x * se[0*FD+o+0] + v.y * se[0*FD+o+1] + v.z * se[0*FD+o+2] + v.w * se[0*FD+o+3];
        a1 += v.x * se[1*FD+o+0] + v.y * se[1*FD+o+1] + v.z * se[1*FD+o+2] + v.w * se[1*FD+o+3];
        a2 += v.x * se[2*FD+o+0] + v.y * se[2*FD+o+1] + v.z * se[2*FD+o+2] + v.w * se[2*FD+o+3];
        a3 += v.x * se[3*FD+o+0] + v.y * se[3*FD+o+1] + v.z * se[3*FD+o+2] + v.w * se[3*FD+o+3];
    }
}

static __device__ __forceinline__ void block_reduce4(float z0, float z1, float z2,
                                                     float z3, float* dst, int j) {
    __shared__ float sred[256];
    float zs[NBR] = {z0, z1, z2, z3};
    for (int i = 0; i < NBR; ++i) {
        sred[threadIdx.x] = zs[i];
        __syncthreads();
        for (int off = 128; off > 0; off >>= 1) {
            if ((int)threadIdx.x < off) sred[threadIdx.x] += sred[threadIdx.x + off];
            __syncthreads();
        }
        if (threadIdx.x == 0) atomicAdd(&dst[i * NBR + j], sred[0]);
        __syncthreads();
    }
}

static __device__ __forceinline__ float term_of(float ex, float zinv, int k) {
    const float c = MPN + EPS_C;
    float v = ex * zinv;
    if (k == 0) return -__logf(1.0f + c / v);
    return -__logf(1.0f + (v + EPS_C) * (1.0f / MPN));
}

template <bool STORE>
__global__ void k_pass1_f32(const float* __restrict__ e, const float* __restrict__ memory,
                            const int* __restrict__ cidx,
                            float* __restrict__ Zsum, ushort4* __restrict__ expS) {
    const int j = blockIdx.z;
    const int b = blockIdx.y;

    __shared__ float s_e[NBR * FD];
    for (int t = threadIdx.x; t < NBR * FD; t += blockDim.x) {
        int i = t >> 7, d = t & (FD - 1);
        s_e[t] = e[((size_t)i * BN + b) * FD + d];
    }
    __syncthreads();

    const int* ci = cidx + (size_t)b * KP1;
    const float4* mem4 = (const float4*)(memory + (size_t)j * NDATA * FD);
    float z0 = 0.f, z1 = 0.f, z2 = 0.f, z3 = 0.f;

    for (int k = threadIdx.x + blockIdx.x * blockDim.x; k < KP1;
         k += blockDim.x * gridDim.x) {
        const int n = ci[k];
        const float4* row = mem4 + (size_t)n * (FD / 4);
        float a0, a1, a2, a3;
        dot4(row, s_e, a0, a1, a2, a3);
        float x0 = __expf(a0 * TINV);
        float x1 = __expf(a1 * TINV);
        float x2 = __expf(a2 * TINV);
        float x3 = __expf(a3 * TINV);
        z0 += x0; z1 += x1; z2 += x2; z3 += x3;
        if (STORE) {
            ushort4 st;
            st.x = f2bf(x0); st.y = f2bf(x1); st.z = f2bf(x2); st.w = f2bf(x3);
            expS[((size_t)j * BN + b) * KP1 + k] = st;
        }
    }
    block_reduce4(z0, z1, z2, z3, Zsum, j);
}

__global__ void k_pass2_stored(const ushort4* __restrict__ expS,
                               const float* __restrict__ Zsum,
                               float* __restrict__ accum) {
    const int j = blockIdx.z;
    const int b = blockIdx.y;

    __shared__ float s_zinv[NBR];
    if (threadIdx.x < NBR) {
        float Z = Zsum[threadIdx.x * NBR + j] *
                  (float)((double)NDATA / ((double)BN * (double)KP1));
        s_zinv[threadIdx.x] = 1.0f / Z;
    }
    __syncthreads();

    const ushort4* es = expS + ((size_t)j * BN + b) * KP1;
    float a0 = 0.f, a1 = 0.f, a2 = 0.f, a3 = 0.f;

    for (int k = threadIdx.x + blockIdx.x * blockDim.x; k < KP1;
         k += blockDim.x * gridDim.x) {
        ushort4 v = es[k];
        a0 += term_of(bf2f(v.x), s_zinv[0], k);
        a1 += term_of(bf2f(v.y), s_zinv[1], k);
        a2 += term_of(bf2f(v.z), s_zinv[2], k);
        a3 += term_of(bf2f(v.w), s_zinv[3], k);
    }
    block_reduce4(a0, a1, a2, a3, accum, j);
}

__global__ void k_pass2_regather(const float* __restrict__ e, const float* __restrict__ memory,
                                 const int* __restrict__ cidx,
                                 const float* __restrict__ Zsum, float* __restrict__ accum) {
    const int j = blockIdx.z;
    const int b = blockIdx.y;

    __shared__ float s_e[NBR * FD];
    __shared__ float s_zinv[NBR];
    for (int t = threadIdx.x; t < NBR * FD; t += blockDim.x) {
        int i = t >> 7, d = t & (FD - 1);
        s_e[t] = e[((size_t)i * BN + b) * FD + d];
    }
    if (threadIdx.x < NBR) {
        float Z = Zsum[threadIdx.x * NBR + j] *
                  (float)((double)NDATA / ((double)BN * (double)KP1));
        s_zinv[threadIdx.x] = 1.0f / Z;
    }
    __syncthreads();

    const int* ci = cidx + (size_t)b * KP1;
    const float4* mem4 = (const float4*)(memory + (size_t)j * NDATA * FD);
    float a0s = 0.f, a1s = 0.f, a2s = 0.f, a3s = 0.f;

    for (int k = threadIdx.x + blockIdx.x * blockDim.x; k < KP1;
         k += blockDim.x * gridDim.x) {
        const int n = ci[k];
        const float4* row = mem4 + (size_t)n * (FD / 4);
        float a0, a1, a2, a3;
        dot4(row, s_e, a0, a1, a2, a3);
        a0s += term_of(__expf(a0 * TINV), s_zinv[0], k);
        a1s += term_of(__expf(a1 * TINV), s_zinv[1], k);
        a2s += term_of(__expf(a2 * TINV), s_zinv[2], k);
        a3s += term_of(__expf(a3 * TINV), s_zinv[3], k);
    }
    block_reduce4(a0s, a1s, a2s, a3s, accum, j);
}

// ---------------------------------------------------------------------------
__global__ void k_init(float* __restrict__ p, int n) {
    int i = blockIdx.x * blockDim.x + threadIdx.x;
    if (i < n) p[i] = 0.f;
}

__global__ void k_final_legacy(const float* __restrict__ accum, float* __restrict__ out) {
    if (threadIdx.x == 0) {
        float s = 0.f;
        for (int i = 0; i < NBR; ++i)
            for (int j = 0; j < NBR; ++j)
                if (i != j) s += -accum[i * NBR + j] / (float)BN;
        out[0] = s;
    }
}

// ---------------------------------------------------------------------------
extern "C" void kernel_launch(void* const* d_in, const int* in_sizes, int n_in,
                              void* d_out, int out_size, void* d_ws, size_t ws_size,
                              hipStream_t stream) {
    const float* e0   = (const float*)d_in[0];
    const float* e1   = (const float*)d_in[1];
    const float* e2   = (const float*)d_in[2];
    const float* e3   = (const float*)d_in[3];
    const float* W    = (const float*)d_in[4];
    const float* bias = (const float*)d_in[5];
    const float* mem  = (const float*)d_in[6];
    const int*   cidx = (const int*)d_in[8];
    float* out = (float*)d_out;

    // ws (floats): e[65536] | Zsum[16] | accum[16] | Zsl[1024] | Asl[1024] | memT | expS
    float* ws    = (float*)d_ws;
    float* e     = ws;
    float* Zsum  = ws + 65536;
    float* accum = ws + 65552;
    float* Zsl   = ws + 65568;
    float* Asl   = ws + 66592;
    const size_t base_b = (size_t)67616 * 4;             // 270,464 B (16-aligned)
    const size_t memT_b = (size_t)NDATA * NBR * FD * 2;  // 102,400,000 B
    const size_t expS_b = (size_t)BN * KP1 * 16 * 2;     // 16,781,312 B

    const size_t need_full = base_b + memT_b + expS_b;   // ~119.45 MB
    const size_t need_mid  = base_b + expS_b;            // ~17.05 MB

    k_init<<<9, 256, 0, stream>>>(Zsum, 2080);  // Zsum+accum+Zsl+Asl
    k_feat<<<dim3(NBR, BN), 128, 0, stream>>>(e0, e1, e2, e3, W, bias, e);

    if (ws_size >= need_full) {
        ushort* memT = (ushort*)((char*)d_ws + base_b);
        ushort* expS = (ushort*)((char*)d_ws + base_b + memT_b);
        k_convert_t<<<50000, 256, 0, stream>>>(mem, memT);
        k_pass1w<<<dim3(16, BN), 256, 0, stream>>>(e, memT, cidx, Zsl, expS);
        k_zred<<<1, 64, 0, stream>>>(Zsl, Zsum);
        k_pass2f<<<dim3(8, BN), 256, 0, stream>>>((const uint4*)expS, Zsum, Asl);
        k_final_slots<<<1, 256, 0, stream>>>(Asl, out);
    } else if (ws_size >= need_mid) {
        ushort4* expS = (ushort4*)((char*)d_ws + base_b);
        k_pass1_f32<true><<<dim3(4, BN, NBR), 256, 0, stream>>>(e, mem, cidx, Zsum, expS);
        k_pass2_stored<<<dim3(4, BN, NBR), 256, 0, stream>>>(expS, Zsum, accum);
        k_final_legacy<<<1, 64, 0, stream>>>(accum, out);
    } else {
        k_pass1_f32<false><<<dim3(4, BN, NBR), 256, 0, stream>>>(e, mem, cidx, Zsum, nullptr);
        k_pass2_regather<<<dim3(4, BN, NBR), 256, 0, stream>>>(e, mem, cidx, Zsum, accum);
        k_final_legacy<<<1, 64, 0, stream>>>(accum, out);
    }
}